// Round 14
// baseline (3336.538 us; speedup 1.0000x reference)
//
#include <hip/hip_runtime.h>
#include <hip/hip_cooperative_groups.h>
#include <math.h>

namespace cg = cooperative_groups;

#define B 256
#define N 1152
#define C_ 10
#define OUT 16
#define IN 8
#define KO 160          // C_*OUT

#define MB 16           // batch rows per unit
#define NC 12           // n per chunk
#define NCH 96          // N/NC -> slab 15.7 MB
#define KG 5            // capsules per unit (2 kg halves)
#define XSTR 100        // NC*8+4 padded x row stride
#define NUNITS 3072     // 8 XCD * 12 chl * 2 kg * 16 bt
#define R1BLKS 2560     // 640 e-groups * 4 chunk-quarters
#define R2BLKS 640

// ---------------- phase S: slab[ch][b][k*16+o] = sum_n softmax(bij)[n,k]*(W.x)
// softmax computed inline from bij (bij=0 at it0 -> exactly 0.1 per lane).
__device__ __forceinline__ void phaseS(
    int u, const float* __restrict__ x, const float* __restrict__ W,
    const float* __restrict__ bij, float* __restrict__ slab,
    float xs[MB][XSTR], float* cs)
{
    const int tid = threadIdx.x;
    const int g = u & 7, q = u >> 3;
    const int bt = q & 15, kg = (q >> 4) & 1, chl = q >> 5;
    const int ch = g * 12 + chl;
    const int b0 = bt * MB, n0 = ch * NC, k0 = kg * KG;

    for (int idx = tid; idx < MB * (NC * 2); idx += 64) {
        int bl = idx / (NC * 2), r = idx - bl * (NC * 2);
        float4 val = *(const float4*)(x + (size_t)(b0 + bl) * (N * IN) + (size_t)n0 * IN + r * 4);
        *(float4*)(&xs[bl][r * 4]) = val;
    }
    if (tid < NC * KG) {            // 60 threads: one (nl,kk) each
        int nl = tid / KG, kk = tid - nl * KG;
        const float* br = bij + (size_t)(n0 + nl) * C_;
        float bv[C_], m = -1e30f;
#pragma unroll
        for (int j = 0; j < C_; ++j) { bv[j] = br[j]; m = fmaxf(m, bv[j]); }
        float ssum = 0.f;
#pragma unroll
        for (int j = 0; j < C_; ++j) ssum += __expf(bv[j] - m);
        cs[tid] = __expf(bv[k0 + kk] - m) / ssum;
    }
    __syncthreads();

    const int o = tid & 15, grp = (tid >> 4) * 4;
    float acc[4][KG];
#pragma unroll
    for (int r = 0; r < 4; ++r)
#pragma unroll
        for (int kk = 0; kk < KG; ++kk) acc[r][kk] = 0.f;

    const float* Wb = W + (size_t)n0 * (KO * IN) + (size_t)(k0 * OUT + o) * IN;

    for (int nl = 0; nl < NC; ++nl) {
        const float* Wn = Wb + (size_t)nl * (KO * IN);
        float4 w[KG][2];
#pragma unroll
        for (int kk = 0; kk < KG; ++kk) {
            w[kk][0] = *(const float4*)(Wn + kk * (OUT * IN));
            w[kk][1] = *(const float4*)(Wn + kk * (OUT * IN) + 4);
        }
        float4 xr[4][2];
#pragma unroll
        for (int r = 0; r < 4; ++r) {
            xr[r][0] = *(const float4*)(&xs[grp + r][nl * IN]);
            xr[r][1] = *(const float4*)(&xs[grp + r][nl * IN + 4]);
        }
#pragma unroll
        for (int kk = 0; kk < KG; ++kk) {
            float cw = cs[nl * KG + kk];
#pragma unroll
            for (int r = 0; r < 4; ++r) {
                float d = w[kk][0].x * xr[r][0].x + w[kk][0].y * xr[r][0].y
                        + w[kk][0].z * xr[r][0].z + w[kk][0].w * xr[r][0].w
                        + w[kk][1].x * xr[r][1].x + w[kk][1].y * xr[r][1].y
                        + w[kk][1].z * xr[r][1].z + w[kk][1].w * xr[r][1].w;
                acc[r][kk] += cw * d;
            }
        }
    }

#pragma unroll
    for (int r = 0; r < 4; ++r) {
        float* pp = slab + (size_t)ch * (B * KO) + (size_t)(b0 + grp + r) * KO
                  + (size_t)k0 * OUT + o;
#pragma unroll
        for (int kk = 0; kk < KG; ++kk) pp[kk * OUT] = acc[r][kk];
    }
}

// ---------------- phase R1: p2[qt][e] = sum of 24 chunks
__device__ __forceinline__ void phaseR1(
    int rb, const float* __restrict__ slab, float* __restrict__ p2)
{
    const int e  = (rb >> 2) * 64 + threadIdx.x;
    const int qt = rb & 3;
    float s = 0.f;
#pragma unroll
    for (int i = 0; i < NCH / 4; ++i)
        s += slab[(size_t)(qt * (NCH / 4) + i) * (B * KO) + e];
    p2[(size_t)qt * (B * KO) + e] = s;
}

// ---------------- phase R2: v = squash(sum of 4 quarters); out on last iter
__device__ __forceinline__ void phaseR2(
    int rb, const float* __restrict__ p2, float* __restrict__ v, float* __restrict__ out)
{
    const int e = rb * 64 + threadIdx.x;
    float s = p2[e] + p2[(size_t)(B * KO) + e]
            + p2[2 * (size_t)(B * KO) + e] + p2[3 * (size_t)(B * KO) + e];
    float vv = s * fabsf(s) / (1.f + s * s);
    v[e] = vv;
    if (out) out[e] = vv;
}

// ---------------- phase A: bij[n][k] += (1/B) sum_{b-tile,o} (W.x)*v   (device atomics)
__device__ __forceinline__ void phaseA(
    int u, const float* __restrict__ x, const float* __restrict__ W,
    const float* __restrict__ v, float* __restrict__ bij,
    float xs[MB][XSTR])
{
    const int tid = threadIdx.x;
    const int g = u & 7, q = u >> 3;
    const int bt = q & 15, kg = (q >> 4) & 1, chl = q >> 5;
    const int ch = g * 12 + chl;
    const int b0 = bt * MB, n0 = ch * NC, k0 = kg * KG;

    for (int idx = tid; idx < MB * (NC * 2); idx += 64) {
        int bl = idx / (NC * 2), r = idx - bl * (NC * 2);
        float4 val = *(const float4*)(x + (size_t)(b0 + bl) * (N * IN) + (size_t)n0 * IN + r * 4);
        *(float4*)(&xs[bl][r * 4]) = val;
    }
    __syncthreads();

    const int o = tid & 15, grp = (tid >> 4) * 4;

    float vv[4][KG];
#pragma unroll
    for (int r = 0; r < 4; ++r) {
        const float* vb = v + (size_t)(b0 + grp + r) * KO + (size_t)k0 * OUT + o;
#pragma unroll
        for (int kk = 0; kk < KG; ++kk) vv[r][kk] = vb[kk * OUT];
    }

    const float* Wb = W + (size_t)n0 * (KO * IN) + (size_t)(k0 * OUT + o) * IN;

    for (int nl = 0; nl < NC; ++nl) {
        const float* Wn = Wb + (size_t)nl * (KO * IN);
        float4 w[KG][2];
#pragma unroll
        for (int kk = 0; kk < KG; ++kk) {
            w[kk][0] = *(const float4*)(Wn + kk * (OUT * IN));
            w[kk][1] = *(const float4*)(Wn + kk * (OUT * IN) + 4);
        }
        float4 xr[4][2];
#pragma unroll
        for (int r = 0; r < 4; ++r) {
            xr[r][0] = *(const float4*)(&xs[grp + r][nl * IN]);
            xr[r][1] = *(const float4*)(&xs[grp + r][nl * IN + 4]);
        }
        float p[KG];
#pragma unroll
        for (int kk = 0; kk < KG; ++kk) p[kk] = 0.f;
#pragma unroll
        for (int kk = 0; kk < KG; ++kk) {
#pragma unroll
            for (int r = 0; r < 4; ++r) {
                float d = w[kk][0].x * xr[r][0].x + w[kk][0].y * xr[r][0].y
                        + w[kk][0].z * xr[r][0].z + w[kk][0].w * xr[r][0].w
                        + w[kk][1].x * xr[r][1].x + w[kk][1].y * xr[r][1].y
                        + w[kk][1].z * xr[r][1].z + w[kk][1].w * xr[r][1].w;
                p[kk] += d * vv[r][kk];
            }
        }
        // 5 interleaved 4-level butterflies over the 16 o-lanes
#pragma unroll
        for (int lv = 1; lv <= 8; lv <<= 1) {
#pragma unroll
            for (int kk = 0; kk < KG; ++kk) p[kk] += __shfl_xor(p[kk], lv);
        }
#pragma unroll
        for (int kk = 0; kk < KG; ++kk)
            if (o == kk)
                atomicAdd(bij + (size_t)(n0 + nl) * C_ + k0 + kk, p[kk] * (1.0f / B));
    }
}

// ================ cooperative fused kernel: all 3 routing iterations ================
__global__ __launch_bounds__(64, 4) void k_coop(
    const float* __restrict__ x, const float* __restrict__ W,
    float* __restrict__ slab, float* __restrict__ p2,
    float* __restrict__ bij, float* __restrict__ v, float* __restrict__ out)
{
    __shared__ float xs[MB][XSTR];
    __shared__ float cs[NC * KG];
    cg::grid_group grid = cg::this_grid();
    const int nb = gridDim.x;

#pragma unroll 1
    for (int it = 0; it < 3; ++it) {
        for (int u = blockIdx.x; u < NUNITS; u += nb)
            phaseS(u, x, W, bij, slab, xs, cs);
        __threadfence(); grid.sync(); __threadfence();

        for (int rb = blockIdx.x; rb < R1BLKS; rb += nb)
            phaseR1(rb, slab, p2);
        __threadfence(); grid.sync(); __threadfence();

        for (int rb = blockIdx.x; rb < R2BLKS; rb += nb)
            phaseR2(rb, p2, v, (it == 2) ? out : nullptr);

        if (it < 2) {
            __threadfence(); grid.sync(); __threadfence();
            for (int u = blockIdx.x; u < NUNITS; u += nb)
                phaseA(u, x, W, v, bij, xs);
            __threadfence(); grid.sync(); __threadfence();
        }
    }
}

// ================ fallback discrete kernels (if cooperative launch rejected) ========
__global__ __launch_bounds__(64, 4) void k_S(
    const float* __restrict__ x, const float* __restrict__ W,
    const float* __restrict__ bij, float* __restrict__ slab)
{
    __shared__ float xs[MB][XSTR];
    __shared__ float cs[NC * KG];
    phaseS(blockIdx.x, x, W, bij, slab, xs, cs);
}
__global__ __launch_bounds__(64) void k_R1(
    const float* __restrict__ slab, float* __restrict__ p2)
{ phaseR1(blockIdx.x, slab, p2); }
__global__ __launch_bounds__(64) void k_R2(
    const float* __restrict__ p2, float* __restrict__ v, float* __restrict__ out)
{ phaseR2(blockIdx.x, p2, v, out); }
__global__ __launch_bounds__(64, 4) void k_A(
    const float* __restrict__ x, const float* __restrict__ W,
    const float* __restrict__ v, float* __restrict__ bij)
{
    __shared__ float xs[MB][XSTR];
    phaseA(blockIdx.x, x, W, v, bij, xs);
}

extern "C" void kernel_launch(void* const* d_in, const int* in_sizes, int n_in,
                              void* d_out, int out_size, void* d_ws, size_t ws_size,
                              hipStream_t stream)
{
    const float* x = (const float*)d_in[0];   // [B, N, IN]
    const float* W = (const float*)d_in[1];   // [1, N, C, OUT, IN]
    float* out = (float*)d_out;               // 40960 floats
    float* ws  = (float*)d_ws;

    float* slab = ws;                         // 96*40960 = 3932160
    float* p2   = ws + 3932160;               // 4*40960 = 163840
    float* bij  = p2 + 163840;                // 11520 (atomic accumulator)
    float* v    = bij + 11520;                // 40960

    // zero bij once per call (it0 softmax reads it -> exactly 0.1)
    hipMemsetAsync(bij, 0, 11520 * sizeof(float), stream);

    int maxB = 0;
    hipError_t qe = hipOccupancyMaxActiveBlocksPerMultiprocessor(
        &maxB, (const void*)k_coop, 64, 0);
    int grid = NUNITS;
    if (qe == hipSuccess && maxB > 0 && maxB * 256 < NUNITS) grid = maxB * 256;

    void* args[] = { (void*)&x, (void*)&W, (void*)&slab, (void*)&p2,
                     (void*)&bij, (void*)&v, (void*)&out };
    hipError_t e = hipLaunchCooperativeKernel(
        (const void*)k_coop, dim3(grid), dim3(64), args, 0, stream);

    if (e != hipSuccess) {
        // discrete fallback: same phases as separate dispatches
        for (int it = 0; it < 3; ++it) {
            k_S <<<NUNITS, 64, 0, stream>>>(x, W, bij, slab);
            k_R1<<<R1BLKS, 64, 0, stream>>>(slab, p2);
            k_R2<<<R2BLKS, 64, 0, stream>>>(p2, v, (it == 2) ? out : nullptr);
            if (it < 2)
                k_A<<<NUNITS, 64, 0, stream>>>(x, W, v, bij);
        }
    }
}

// Round 16
// 142.237 us; speedup vs baseline: 23.4575x; 23.4575x over previous
//
#include <hip/hip_runtime.h>
#include <math.h>

#define B 256
#define N 1152
#define C_ 10
#define OUT 16
#define IN 8
#define KO 160          // C_*OUT

// ---- s-partial geometry: 64-thread blocks, BT=4, KG=5, NC=18 -> slab 10.5 MB
#define MB 16
#define NC 18
#define NCH 64          // N/NC -> slab 64*40960 floats = 10.5 MB (1.3 MB/XCD)
#define KG 5
#define XSTR 148        // NC*8+4: rows at banks {0,20,8,28} for grp rows -> conflict-free

// partial[ch][b][k*16+o] = sum_{n in chunk} c[n,k]*(W[n,k,o,:].x[b,n,:])
// grid 2048 = 8 XCD * 8 chl * 2 kg * 16 bt (bt fastest -> 16 blocks share one W chunk)
__global__ __launch_bounds__(64, 4) void k_s_partial(
    const float* __restrict__ x, const float* __restrict__ W,
    const float* __restrict__ c, float* __restrict__ partial)
{
    __shared__ float xs[MB][XSTR];      // 9.5 KB
    __shared__ float cs[NC][KG];

    const int tid = threadIdx.x;
    const int id  = blockIdx.x;
    const int g   = id & 7;
    const int q   = id >> 3;            // 0..255
    const int bt  = q & 15;
    const int kg  = (q >> 4) & 1;
    const int chl = q >> 5;             // 0..7
    const int ch  = g * 8 + chl;        // 0..63
    const int b0  = bt * MB;
    const int n0  = ch * NC;
    const int k0  = kg * KG;

    for (int idx = tid; idx < MB * (NC * 2); idx += 64) {   // 16 rows x 36 float4
        int bl = idx / (NC * 2), r = idx - bl * (NC * 2);
        float4 val = *(const float4*)(x + (size_t)(b0 + bl) * (N * IN) + (size_t)n0 * IN + r * 4);
        *(float4*)(&xs[bl][r * 4]) = val;
    }
    if (c) {
        for (int idx = tid; idx < NC * KG; idx += 64) {
            int nl = idx / KG, kk = idx - nl * KG;
            cs[nl][kk] = c[(size_t)(n0 + nl) * C_ + (k0 + kk)];
        }
    }
    __syncthreads();

    const int o   = tid & 15;
    const int grp = (tid >> 4) * 4;

    float acc[4][KG];
#pragma unroll
    for (int r = 0; r < 4; ++r)
#pragma unroll
        for (int kk = 0; kk < KG; ++kk) acc[r][kk] = 0.f;

    const float* Wb = W + (size_t)n0 * (KO * IN) + (size_t)(k0 * OUT + o) * IN;

    for (int nl = 0; nl < NC; ++nl) {
        const float* Wn = Wb + (size_t)nl * (KO * IN);
        float4 w[KG][2];
#pragma unroll
        for (int kk = 0; kk < KG; ++kk) {
            w[kk][0] = *(const float4*)(Wn + kk * (OUT * IN));
            w[kk][1] = *(const float4*)(Wn + kk * (OUT * IN) + 4);
        }
        float4 xr[4][2];
#pragma unroll
        for (int r = 0; r < 4; ++r) {
            xr[r][0] = *(const float4*)(&xs[grp + r][nl * IN]);
            xr[r][1] = *(const float4*)(&xs[grp + r][nl * IN + 4]);
        }
        float cw[KG];
#pragma unroll
        for (int kk = 0; kk < KG; ++kk) cw[kk] = c ? cs[nl][kk] : 0.1f;

#pragma unroll
        for (int kk = 0; kk < KG; ++kk) {
#pragma unroll
            for (int r = 0; r < 4; ++r) {
                float d = w[kk][0].x * xr[r][0].x + w[kk][0].y * xr[r][0].y
                        + w[kk][0].z * xr[r][0].z + w[kk][0].w * xr[r][0].w
                        + w[kk][1].x * xr[r][1].x + w[kk][1].y * xr[r][1].y
                        + w[kk][1].z * xr[r][1].z + w[kk][1].w * xr[r][1].w;
                acc[r][kk] += cw[kk] * d;
            }
        }
    }

#pragma unroll
    for (int r = 0; r < 4; ++r) {
        float* pp = partial + (size_t)ch * (B * KO) + (size_t)(b0 + grp + r) * KO
                  + (size_t)k0 * OUT + o;
#pragma unroll
        for (int kk = 0; kk < KG; ++kk) pp[kk * OUT] = acc[r][kk];
    }
}

// ---------------- reduce partials over 64 chunks + squash
__global__ __launch_bounds__(256) void k_reduce_squash(
    const float* __restrict__ partial, float* __restrict__ v, float* __restrict__ out)
{
    __shared__ float red[256];
    const int tid = threadIdx.x;
    const int e   = blockIdx.x * 64 + (tid & 63);
    const int q   = tid >> 6;
    float s = 0.f;
#pragma unroll
    for (int i = 0; i < NCH / 4; ++i)
        s += partial[(size_t)(q * (NCH / 4) + i) * (B * KO) + e];
    red[tid] = s;
    __syncthreads();
    if (q == 0) {
        s = red[tid] + red[tid + 64] + red[tid + 128] + red[tid + 192];
        float vv = s * fabsf(s) / (1.f + s * s);
        v[e] = vv;
        if (out) out[e] = vv;
    }
}

// ---------------- x transpose: xt[n][b][i] = x[b][n][i]  (once per launch)
__global__ __launch_bounds__(256) void k_xT(
    const float* __restrict__ x, float* __restrict__ xt)
{
    __shared__ float t[32][32 * IN + 4];
    const int bb0 = (blockIdx.x & 7) * 32;
    const int nn0 = (blockIdx.x >> 3) * 32;

    for (int idx = threadIdx.x; idx < 32 * 64; idx += 256) {
        int b = idx >> 6, r = idx & 63;
        float4 val = *(const float4*)(x + (size_t)(bb0 + b) * (N * IN) + (size_t)nn0 * IN + r * 4);
        *(float4*)(&t[b][r * 4]) = val;
    }
    __syncthreads();
    for (int idx = threadIdx.x; idx < 32 * 64; idx += 256) {
        int n = idx >> 6, r = idx & 63;
        int b = r >> 1, i = (r & 1) * 4;
        float4 val = *(const float4*)(&t[b][n * IN + i]);
        *(float4*)(xt + (size_t)(nn0 + n) * (B * IN) + (size_t)(bb0 + b) * IN + i) = val;
    }
}

// ---------------- a-pass + fused softmax; W slice in 20 float4 registers.
// Hardened vs R15: W loads issued AFTER the staging barrier.
__global__ __launch_bounds__(256) void k_a_sm(
    const float* __restrict__ xt, const float* __restrict__ W,
    const float* __restrict__ v, float* __restrict__ bij,
    float* __restrict__ c_out, int accumulate)
{
    const int n = blockIdx.x;
    const int tid = threadIdx.x;

    __shared__ float xtl[B][IN];          // 8 KB
    __shared__ float red[4][16][C_];
    __shared__ float bnew[C_];

    const int o = tid & 15;
    const int blane = tid >> 4;

    // stage xt coalesced: xt[n] is 2048 contiguous floats
    {
        const float4* src = (const float4*)(xt + (size_t)n * (B * IN));
        for (int idx = tid; idx < B * IN / 4; idx += 256)
            *(float4*)(&xtl[idx >> 1][(idx & 1) * 4]) = src[idx];
    }
    __syncthreads();

    // W slice into registers: coalesced (16 lanes x 32B = 512B contiguous per k)
    const float* Wb = W + (size_t)n * (KO * IN) + o * IN;
    float4 w0[C_], w1[C_];
#pragma unroll
    for (int k = 0; k < C_; ++k) {
        w0[k] = *(const float4*)(Wb + k * (OUT * IN));
        w1[k] = *(const float4*)(Wb + k * (OUT * IN) + 4);
    }

    float part[C_];
#pragma unroll
    for (int k = 0; k < C_; ++k) part[k] = 0.f;

    for (int t = 0; t < B / 16; ++t) {
        int bb = blane + t * 16;
        float4 xv0 = *(const float4*)(&xtl[bb][0]);
        float4 xv1 = *(const float4*)(&xtl[bb][4]);
        const float* vb = v + (size_t)bb * KO + o;
        float vv[C_];
#pragma unroll
        for (int k = 0; k < C_; ++k) vv[k] = vb[k * OUT];
#pragma unroll
        for (int k = 0; k < C_; ++k) {
            float d = w0[k].x * xv0.x + w0[k].y * xv0.y + w0[k].z * xv0.z + w0[k].w * xv0.w
                    + w1[k].x * xv1.x + w1[k].y * xv1.y + w1[k].z * xv1.z + w1[k].w * xv1.w;
            part[k] += d * vv[k];
        }
    }

    // reduce: shfl over the 4 blane groups per wave, then LDS across waves
    const int wv = tid >> 6;
#pragma unroll
    for (int k = 0; k < C_; ++k) {
        float p = part[k];
        p += __shfl_xor(p, 16);
        p += __shfl_xor(p, 32);
        part[k] = p;
    }
    if ((tid & 63) < 16) {
#pragma unroll
        for (int k = 0; k < C_; ++k) red[wv][o][k] = part[k];
    }
    __syncthreads();

    if (tid < C_) {
        float a = 0.f;
#pragma unroll
        for (int w = 0; w < 4; ++w)
#pragma unroll
            for (int oo = 0; oo < 16; ++oo) a += red[w][oo][tid];
        a *= (1.0f / B);
        float bo = accumulate ? bij[(size_t)n * C_ + tid] : 0.f;
        float bn = bo + a;
        bij[(size_t)n * C_ + tid] = bn;
        bnew[tid] = bn;
    }
    __syncthreads();
    if (tid < C_) {
        float m = -1e30f;
#pragma unroll
        for (int k = 0; k < C_; ++k) m = fmaxf(m, bnew[k]);
        float ssum = 0.f;
#pragma unroll
        for (int k = 0; k < C_; ++k) ssum += __expf(bnew[k] - m);
        c_out[(size_t)n * C_ + tid] = __expf(bnew[tid] - m) / ssum;
    }
}

extern "C" void kernel_launch(void* const* d_in, const int* in_sizes, int n_in,
                              void* d_out, int out_size, void* d_ws, size_t ws_size,
                              hipStream_t stream)
{
    const float* x = (const float*)d_in[0];   // [B, N, IN]
    const float* W = (const float*)d_in[1];   // [1, N, C, OUT, IN]
    float* out = (float*)d_out;               // [B, C, OUT, 1] = 40960 floats
    float* ws  = (float*)d_ws;

    float* part = ws;                         // 64 * 40960 = 2621440 floats (10.5 MB)
    float* bij  = ws + 2621440;               // 11520
    float* c    = bij + 11520;                // 11520
    float* v    = c + 11520;                  // 40960
    float* xt   = v + 40960;                  // 2359296 floats (9.4 MB)

    const int GS = 2048;                      // 8 XCD * 8 chl * 2 kg * 16 bt

    k_xT<<<288, 256, 0, stream>>>(x, xt);

    // iteration 0: c = 1/C exactly (softmax of zeros)
    k_s_partial<<<GS, 64, 0, stream>>>(x, W, nullptr, part);
    k_reduce_squash<<<640, 256, 0, stream>>>(part, v, nullptr);
    k_a_sm<<<N, 256, 0, stream>>>(xt, W, v, bij, c, 0);

    // iteration 1
    k_s_partial<<<GS, 64, 0, stream>>>(x, W, c, part);
    k_reduce_squash<<<640, 256, 0, stream>>>(part, v, nullptr);
    k_a_sm<<<N, 256, 0, stream>>>(xt, W, v, bij, c, 1);

    // iteration 2 (final: write d_out)
    k_s_partial<<<GS, 64, 0, stream>>>(x, W, c, part);
    k_reduce_squash<<<640, 256, 0, stream>>>(part, v, out);
}